// Round 9
// baseline (208.240 us; speedup 1.0000x reference)
//
#include <hip/hip_runtime.h>

// ---------------------------------------------------------------------------
// GenView, round 18.
//
// Algebra (verified R1-R8): per-row softmax cancels emb[row]·w1 and biases.
//   q[n]    = feat[n] . (W @ w2)
//   t[n]    = exp( sum_{e:row=n} v[e]*q[col[e]] )
//   invS[n] = 1 / sum_{e:row=n} t[col[e]]
//   out[e]  = vori[e] + t[col[e]] * invS[row[e]]
//
// Findings ledger:
//  R9  207.8us: SB=256 sort || GB=782 gemv, 5 dispatches.   <- tied best
//  R11 grid.sync ~60us/sync -> dead end.
//  R12 sort->gemv serialized per block: k_fused1r=62us, VALU 4%.
//  R13 recE+k_finish scatter fusion: +7us (scattered 4B out-writes).
//  R14 atomic row dispenser: 147us (same-line device RMW serialized).
//  R15 CPAD padding alone: NEUTRAL -> reserve atomics never the bottleneck.
//  R17 SB=512 interleaved sort: NEUTRAL (208.1) -> sort throughput NOT the
//      long pole either. k_fused is gemv/feat-side bound; floor is
//      2x60us fills + restores + ~4 gaps (harness-fixed, ~145us).
// R18: gemv latency test. Per-row body was a dependent chain (2 loads ->
// 8 FMA -> 6 DS-pipe shuffles -> store). Now each wave does a consecutive
// ROW PAIR: 4 loads issued up front (2x MLP), two INDEPENDENT reduction
// chains (interleavable), one aligned float2 store for both q values.
// If neutral -> gemv is BW-bound and controllable budget is at its
// structural floor. Everything else byte-identical to R17.
// Bucket sort: row>>7 -> 391 buckets, CAP=3072 (mean fill 2046, 22 sigma).
// ---------------------------------------------------------------------------

typedef unsigned int u32;

#define RPB     128          // rows per bucket
#define CAP     3072         // record slots per bucket
#define NB_MAX  512          // max buckets (N <= 65536)
#define CPAD    16           // cnt[] stride in u32 (one 64B line per counter)
#define SB      512          // sort blocks (even blockIdx < 2*SB)
#define GB      782          // gemv blocks (16 waves each -> 12512 waves)

// ---- u2[f] = sum_h W[f,h]*mw[H+h]; block 0 also zeros cnt[] ----
__global__ void k_prep(const float* __restrict__ W, const float* __restrict__ mw,
                       float* __restrict__ u2, u32* __restrict__ cnt,
                       int F, int H, int nz) {
  if (blockIdx.x == 0)
    for (int s = threadIdx.x; s < nz; s += blockDim.x) cnt[s] = 0;
  int f = blockIdx.x * blockDim.x + threadIdx.x;
  if (f >= F) return;
  const float4* wr = (const float4*)(W + (size_t)f * H);
  const float4* mv = (const float4*)(mw + H);
  float s = 0.f;
  for (int i = 0; i < H / 4; ++i) {
    float4 a = wr[i], b = mv[i];
    s = fmaf(a.x, b.x, fmaf(a.y, b.y, fmaf(a.z, b.z, fmaf(a.w, b.w, s))));
  }
  u2[f] = s;
}

// ---- fused, interleaved roles:
//   blockIdx < 2*SB:  even -> sort (id = blockIdx/2), odd -> gemv (id = blockIdx/2)
//   blockIdx >= 2*SB: gemv (id = blockIdx - SB)
// sort: rec8[slot] = (col<<7 | row&127, bits(v)); LDS hist -> global
//       reserve (padded counters) -> scatter.
// gemv: 64 lanes/row-pair, 4 loads in flight, two independent reductions.
template <int F>
__global__ void __launch_bounds__(1024)
k_fused(const int* __restrict__ row, const int* __restrict__ col,
        const float* __restrict__ v, const float* __restrict__ feat,
        const float* __restrict__ u2, float* __restrict__ q,
        u32* __restrict__ cnt, uint2* __restrict__ rec8,
        int E, int N, int nb) {
  __shared__ u32 h[NB_MAX];
  __shared__ u32 start[NB_MAX];
  const int tid = threadIdx.x;
  const int bid = blockIdx.x;

  const bool is_sort = (bid < 2 * SB) && ((bid & 1) == 0);

  if (is_sort) {
    // ---------------- sort path ----------------
    const int sid   = bid >> 1;                 // 0..SB-1
    const int chunk = (E + SB - 1) / SB;        // ~1563
    for (int s = tid; s < nb; s += blockDim.x) h[s] = 0;
    __syncthreads();
    const int lo = sid * chunk;
    const int hi = min(E, lo + chunk);
    for (int e = lo + tid; e < hi; e += blockDim.x)
      atomicAdd(&h[row[e] >> 7], 1u);
    __syncthreads();
    for (int s = tid; s < nb; s += blockDim.x) {
      u32 c = h[s];
      start[s] = c ? atomicAdd(&cnt[(size_t)s * CPAD], c) : 0u; // 1 line/ctr
      h[s] = 0u;                                                // local rank
    }
    __syncthreads();
    for (int e = lo + tid; e < hi; e += blockDim.x) {
      int r = row[e];
      int b = r >> 7;
      u32 rank = atomicAdd(&h[b], 1u);
      u32 off  = min(start[b] + rank, (u32)CAP - 1);  // memory-safety clamp
      rec8[(size_t)b * CAP + off] =
          make_uint2(((u32)col[e] << 7) | (u32)(r & 127),
                     __float_as_uint(v[e]));
    }
  } else {
    // ---------------- gemv path: row pairs ----------------
    const int gid  = (bid < 2 * SB) ? (bid >> 1) : (bid - SB);  // 0..GB-1
    const int lane = tid & 63;
    const float4 ua = *(const float4*)(u2 + lane * 8);
    const float4 ub = *(const float4*)(u2 + lane * 8 + 4);
    const int wid = gid * (1024 >> 6) + (tid >> 6);
    const int nw  = GB * (1024 >> 6);
    const int np  = (N + 1) >> 1;               // row pairs
    for (int p = wid; p < np; p += nw) {
      const int rA = p * 2;
      const int rB = rA + 1;
      const float* fA = feat + (size_t)rA * F + lane * 8;
      // issue all loads up front (4 dwordx4 in flight)
      float4 a0 = *(const float4*)fA;
      float4 b0 = *(const float4*)(fA + 4);
      float4 a1, b1;
      const bool hasB = (rB < N);
      if (hasB) {
        const float* fB = fA + F;
        a1 = *(const float4*)fB;
        b1 = *(const float4*)(fB + 4);
      }
      float s0 = fmaf(a0.x, ua.x, fmaf(a0.y, ua.y, fmaf(a0.z, ua.z,
                 fmaf(a0.w, ua.w, fmaf(b0.x, ub.x, fmaf(b0.y, ub.y,
                 fmaf(b0.z, ub.z, b0.w * ub.w)))))));
      float s1 = 0.f;
      if (hasB)
        s1 = fmaf(a1.x, ua.x, fmaf(a1.y, ua.y, fmaf(a1.z, ua.z,
             fmaf(a1.w, ua.w, fmaf(b1.x, ub.x, fmaf(b1.y, ub.y,
             fmaf(b1.z, ub.z, b1.w * ub.w)))))));
      // two independent reduction chains (compiler interleaves latency)
      s0 += __shfl_xor(s0, 32);  s1 += __shfl_xor(s1, 32);
      s0 += __shfl_xor(s0, 16);  s1 += __shfl_xor(s1, 16);
      s0 += __shfl_xor(s0, 8);   s1 += __shfl_xor(s1, 8);
      s0 += __shfl_xor(s0, 4);   s1 += __shfl_xor(s1, 4);
      s0 += __shfl_xor(s0, 2);   s1 += __shfl_xor(s1, 2);
      s0 += __shfl_xor(s0, 1);   s1 += __shfl_xor(s1, 1);
      if (lane == 0) {
        if (hasB) {
          *(float2*)(q + rA) = make_float2(s0, s1);  // rA even -> aligned
        } else {
          q[rA] = s0;
        }
      }
    }
  }
}

// ---- per-bucket: t[row] = exp( sum v * q[col] ) ----
__global__ void __launch_bounds__(1024)
k_sum_t(const uint2* __restrict__ rec8, const u32* __restrict__ cnt,
        const float* __restrict__ q, float* __restrict__ t) {
  __shared__ float acc[RPB];
  const int b = blockIdx.x;
  const int tid = threadIdx.x;
  if (tid < RPB) acc[tid] = 0.f;
  __syncthreads();
  const u32 lo = (u32)b * CAP;
  const u32 n  = min(cnt[(size_t)b * CPAD], (u32)CAP);
  for (u32 i = tid; i < n; i += blockDim.x) {
    uint2 rr = rec8[lo + i];
    atomicAdd(&acc[rr.x & 127], q[rr.x >> 7] * __uint_as_float(rr.y));
  }
  __syncthreads();
  if (tid < RPB) t[b * RPB + tid] = __expf(acc[tid]);
}

// ---- per-bucket: invS[row] = 1 / sum t[col] ----
__global__ void __launch_bounds__(1024)
k_sum_invS(const uint2* __restrict__ rec8, const u32* __restrict__ cnt,
           const float* __restrict__ t, float* __restrict__ invS) {
  __shared__ float acc[RPB];
  const int b = blockIdx.x;
  const int tid = threadIdx.x;
  if (tid < RPB) acc[tid] = 0.f;
  __syncthreads();
  const u32 lo = (u32)b * CAP;
  const u32 n  = min(cnt[(size_t)b * CPAD], (u32)CAP);
  for (u32 i = tid; i < n; i += blockDim.x) {
    uint2 rr = rec8[lo + i];
    atomicAdd(&acc[rr.x & 127], t[rr.x >> 7]);
  }
  __syncthreads();
  if (tid < RPB) invS[b * RPB + tid] = 1.0f / acc[tid]; // empty rows never read
}

// ---- linear, 4 edges/thread: out[e] = vori[e] + t[col[e]] * invS[row[e]] ----
__global__ void k_out(const int* __restrict__ row, const int* __restrict__ col,
                      const float* __restrict__ vori, const float* __restrict__ t,
                      const float* __restrict__ invS, float* __restrict__ out,
                      int E) {
  int e4 = blockIdx.x * blockDim.x + threadIdx.x;
  int e  = e4 * 4;
  if (e + 3 < E) {
    int4   r4 = *(const int4*)(row + e);
    int4   c4 = *(const int4*)(col + e);
    float4 v4 = *(const float4*)(vori + e);
    float4 o;
    o.x = v4.x + t[c4.x] * invS[r4.x];
    o.y = v4.y + t[c4.y] * invS[r4.y];
    o.z = v4.z + t[c4.z] * invS[r4.z];
    o.w = v4.w + t[c4.w] * invS[r4.w];
    *(float4*)(out + e) = o;
  } else {
    for (; e < E; ++e)
      out[e] = vori[e] + t[col[e]] * invS[row[e]];
  }
}

// ---- fallback path (ws too small / shape mismatch): global-atomic ----
__global__ void k_gemv_fb(const float* __restrict__ feat, const float* __restrict__ u2,
                          float* __restrict__ q, int N, int F) {
  const int lane = threadIdx.x & 63;
  const int wave = (blockIdx.x * blockDim.x + threadIdx.x) >> 6;
  if (wave >= N) return;
  const float* fr = feat + (size_t)wave * F;
  float a = 0.f;
  for (int i = lane; i < F; i += 64) a = fmaf(fr[i], u2[i], a);
  for (int off = 32; off; off >>= 1) a += __shfl_xor(a, off);
  if (lane == 0) q[wave] = a;
}
__global__ void k_scatter_B_at(const int* __restrict__ row, const int* __restrict__ col,
                               const float* __restrict__ v, const float* __restrict__ q,
                               float* __restrict__ B, int E) {
  int e = blockIdx.x * blockDim.x + threadIdx.x;
  if (e >= E) return;
  atomicAdd(&B[row[e]], v[e] * q[col[e]]);
}
__global__ void k_node_t(const float* __restrict__ B, float* __restrict__ t, int N) {
  int n = blockIdx.x * blockDim.x + threadIdx.x;
  if (n < N) t[n] = __expf(B[n]);
}
__global__ void k_scatter_S_at(const int* __restrict__ row, const int* __restrict__ col,
                               const float* __restrict__ t, float* __restrict__ S, int E) {
  int e = blockIdx.x * blockDim.x + threadIdx.x;
  if (e >= E) return;
  atomicAdd(&S[row[e]], t[col[e]]);
}
__global__ void k_out_div(const int* __restrict__ row, const int* __restrict__ col,
                          const float* __restrict__ vori, const float* __restrict__ t,
                          const float* __restrict__ S, float* __restrict__ out, int E) {
  int e = blockIdx.x * blockDim.x + threadIdx.x;
  if (e >= E) return;
  out[e] = vori[e] + t[col[e]] / S[row[e]];
}

extern "C" void kernel_launch(void* const* d_in, const int* in_sizes, int n_in,
                              void* d_out, int out_size, void* d_ws, size_t ws_size,
                              hipStream_t stream) {
  const float* vori = (const float*)d_in[0];
  const float* feat = (const float*)d_in[1];
  const int*   vind = (const int*)d_in[2];
  const float* W    = (const float*)d_in[4];
  const float* mw   = (const float*)d_in[6];

  const int E = in_sizes[0];
  const int H = in_sizes[6] / 2;        // 128
  const int F = in_sizes[4] / H;        // 512
  const int N = in_sizes[1] / F;        // 50000

  const int* row = vind;
  const int* col = vind + E;

  const int nb   = (N + RPB - 1) / RPB; // 391
  const int npad = nb * RPB;

  // ---- workspace: u2(F) q(N) t(npad) invS(npad) | cnt(nb*CPAD u32) |
  //      rec8(nb*CAP uint2)
  float* ws   = (float*)d_ws;
  float* u2   = ws;
  float* q    = u2 + F;
  float* t    = q + N;
  float* invS = t + npad;
  u32*   cnt  = (u32*)(invS + npad);
  size_t hdr  = (size_t)((char*)(cnt + (size_t)nb * CPAD) - (char*)d_ws);
  hdr = (hdr + 63) & ~(size_t)63;
  uint2* rec8 = (uint2*)((char*)d_ws + hdr);
  size_t need = hdr + (size_t)nb * CAP * sizeof(uint2);

  k_prep<<<(F + 255) / 256, 256, 0, stream>>>(W, mw, u2, cnt, F, H, nb * CPAD);

  if (ws_size >= need && F == 512 && H % 4 == 0 && nb <= NB_MAX) {
    k_fused<512><<<SB + GB, 1024, 0, stream>>>(row, col, vori, feat, u2, q,
                                               cnt, rec8, E, N, nb);
    k_sum_t<<<nb, 1024, 0, stream>>>(rec8, cnt, q, t);
    k_sum_invS<<<nb, 1024, 0, stream>>>(rec8, cnt, t, invS);
    const int e4 = (E + 3) / 4;
    k_out<<<(e4 + 255) / 256, 256, 0, stream>>>(row, col, vori, t, invS,
                                                (float*)d_out, E);
  } else {
    const int eb  = (E + 255) / 256;
    const int nbk = (N + 255) / 256;
    float* S = invS;
    k_gemv_fb<<<(N * 64 + 255) / 256, 256, 0, stream>>>(feat, u2, q, N, F);
    hipMemsetAsync((void*)S, 0, sizeof(float) * (size_t)npad, stream);
    k_scatter_B_at<<<eb, 256, 0, stream>>>(row, col, vori, q, S, E);
    k_node_t<<<nbk, 256, 0, stream>>>(S, t, N);
    hipMemsetAsync((void*)S, 0, sizeof(float) * (size_t)npad, stream);
    k_scatter_S_at<<<eb, 256, 0, stream>>>(row, col, t, S, E);
    k_out_div<<<eb, 256, 0, stream>>>(row, col, vori, t, S, (float*)d_out, E);
  }
}